// Round 13
// baseline (35.538 us; speedup 1.0000x reference)
//
#include <hip/hip_runtime.h>

// Problem constants
#define NSTEPS 255
#define NTRAJ  16384
#define NBLK   128          // integration blocks; 2 x 64 trajectories each
#define HALF   8192         // chain-1 trajectory offset

#define GAMMA_F 0.36f
#define OMEGA_F 5.0265f
#define DT_F    0.00390625f          // 2^-8
#define CW      0.0375f              // sqrt(GAMMA)*sqrt(DT) = 0.6/16 (exact)
#define GD      (GAMMA_F * DT_F)
#define OD      (OMEGA_F * DT_F)

// LDS history window: [slot 0..127][entry 0..127] fp16x4 {x,y,z,pad}.
// Entry = chain0 lane (0..63) or 64+lane (chain1). Slot pitch 1032 B
// (1024 + 8 pad): per-step writes are 128 consecutive 8B (free); tail reads
// lane-stride 1032 -> start bank 2s mod 32 -> 4-way (~1.58x, acceptable).
#define HPITCH 1032
#define HBYTES (128 * HPITCH)   // 132096 B

typedef __fp16 half2v __attribute__((ext_vector_type(2)));
typedef float  f32x2  __attribute__((ext_vector_type(2)));

__device__ __forceinline__ unsigned pk2(float a, float b) {
  half2v h = __builtin_amdgcn_cvt_pkrtz(a, b);
  return __builtin_bit_cast(unsigned, h);
}

// One Euler-Maruyama step (bit-identical R4/R7/R9-validated math), explicit
// state refs so two independent chains interleave in one thread.
#define STEP2(v_, z_, wx_, wy_, dst_) {                                         \
  const float w0 = (wx_) * CW;                                                  \
  const float cy = (wy_) * CW;                                                  \
  const f32x2 sw = __builtin_shufflevector(v_, v_, 1, 0);   /* (y,x) */         \
  f32x2 t = __builtin_elementwise_fma(epack, sw, v_);                           \
  t = __builtin_elementwise_fma(mGD2, v_, t);                                   \
  const f32x2 w0s = {w0, w0};                                                   \
  t = __builtin_elementwise_fma(-(v_ * z_), w0s, t);                            \
  const f32x2 cys = {-cy, cy};                                                  \
  t = __builtin_elementwise_fma(sw, cys, t);                                    \
  t[1] = __builtin_fmaf(-OD, z_, t[1]);                                         \
  const float a_ = __builtin_fmaf(OD, v_[1], z_);                               \
  const float r_ = __builtin_fmaf(-(z_ * z_), w0, w0);                          \
  v_ = t; z_ = a_ + r_;                                                         \
  *(uint2*)(dst_) = make_uint2(pk2(v_[0], v_[1]), pk2(z_, 0.0f));               \
}

// Load 16-step chunk CH_ for both chains (cnt CNT: 16, or 15 for chunk 15)
#define LOADC2(B0_, B1_, CH_, CNT) {                                            \
  _Pragma("unroll")                                                             \
  for (int i_ = 0; i_ < (CNT); ++i_) {                                          \
    B0_[i_] = wrow0[(CH_) * 16 + i_];                                           \
    B1_[i_] = wrow1[(CH_) * 16 + i_];                                           \
  }                                                                             \
}

// Run CNT steps of both chains; local window slots LSB..LSB+CNT-1.
#define PROC2(B0_, B1_, LSB, CNT) {                                             \
  _Pragma("unroll")                                                             \
  for (int i_ = 0; i_ < (CNT); ++i_) {                                          \
    STEP2(v0, z0, (B0_)[i_].x, (B0_)[i_].y, hb + ((LSB) + i_) * HPITCH);        \
    STEP2(v1, z1, (B1_)[i_].x, (B1_)[i_].y, hb + ((LSB) + i_) * HPITCH + 512);  \
  }                                                                             \
}

// Reduce window P (NS slots): lane l handles slots l, l+64. Per chain: sum
// entries j=0..63 ascending (same order as R9 per-block tail) -> partial rows
// P*128+s for vb=g (chain0) and vb=128+g (chain1).
#define TAILPASS(P, NS) {                                                       \
  __syncthreads();                                                              \
  _Pragma("unroll")                                                             \
  for (int kk_ = 0; kk_ < 2; ++kk_) {                                           \
    const int s_ = l + 64 * kk_;                                                \
    if (s_ < (NS)) {                                                            \
      const char* rb_ = hist + (size_t)s_ * HPITCH;                             \
      f32x2 sxy0 = {0.0f, 0.0f}, sxy1 = {0.0f, 0.0f};                           \
      float fz0 = 0.0f, fz1 = 0.0f;                                             \
      _Pragma("unroll")                                                         \
      for (int j_ = 0; j_ < 64; ++j_) {                                         \
        const uint2 u0 = *(const uint2*)(rb_ + j_ * 8);                         \
        const uint2 u1 = *(const uint2*)(rb_ + 512 + j_ * 8);                   \
        const half2v xy0 = __builtin_bit_cast(half2v, u0.x);                    \
        const half2v zp0 = __builtin_bit_cast(half2v, u0.y);                    \
        const half2v xy1 = __builtin_bit_cast(half2v, u1.x);                    \
        const half2v zp1 = __builtin_bit_cast(half2v, u1.y);                    \
        const f32x2 a0 = {(float)xy0[0], (float)xy0[1]};                        \
        const f32x2 a1 = {(float)xy1[0], (float)xy1[1]};                        \
        sxy0 += a0; fz0 += (float)zp0[0];                                       \
        sxy1 += a1; fz1 += (float)zp1[0];                                       \
      }                                                                         \
      const int row_ = (P) * 128 + s_;                                          \
      float* p0_ = partial + ((size_t)g * NSTEPS + row_) * 3;                   \
      float* p1_ = partial + ((size_t)(128 + g) * NSTEPS + row_) * 3;           \
      p0_[0] = sxy0[0]; p0_[1] = sxy0[1]; p0_[2] = fz0;                         \
      p1_[0] = sxy1[0]; p1_[1] = sxy1[1]; p1_[2] = fz1;                         \
    }                                                                           \
  }                                                                             \
  __syncthreads();                                                              \
}

// grid = 128 blocks x 64 threads (1 wave). Thread (g,l): trajectories
// n0 = g*64+l (vb g) and n1 = 8192+g*64+l (vb 128+g) — two independent
// chains fill each other's dependency bubbles. Time in two 128-step windows
// with an in-wave reduction after each. Chunks of 16 steps, double-buffered
// (distance 1 = ~32 step-times of load cover).
__global__ __launch_bounds__(64) void sde_integrate(const float* __restrict__ inp,
                                                    const float* __restrict__ wvec,
                                                    float* __restrict__ partial) {
  __shared__ alignas(16) char hist[HBYTES];
  const int g = blockIdx.x, l = threadIdx.x;
  // eps = inputs[n % 32] = inputs[l & 31] for BOTH chains (8192 % 32 == 0)
  const float eps = inp[l & 31];
  const f32x2 epack = {-eps * DT_F, eps * DT_F};
  const f32x2 mGD2  = {-GD, -GD};

  const float2* __restrict__ wrow0 =
      reinterpret_cast<const float2*>(wvec) + (size_t)(g * 64 + l) * NSTEPS;
  const float2* __restrict__ wrow1 =
      reinterpret_cast<const float2*>(wvec) + (size_t)(HALF + g * 64 + l) * NSTEPS;
  char* const hb = hist + l * 8;

  f32x2 v0 = {0.0f, 0.0f}, v1 = {0.0f, 0.0f};
  float z0 = 1.0f, z1 = 1.0f;

  float2 A0[16], A1[16], B0[16], B1[16];   // static indexing only (regs)

  // ---- window 0: chunks 0..7 (steps 0..127 -> slots 0..127) ----
  LOADC2(A0, A1, 0, 16);
  #pragma unroll 1
  for (int k = 0; k < 4; ++k) {
    LOADC2(B0, B1, 2 * k + 1, 16);
    PROC2(A0, A1, 32 * k, 16);
    LOADC2(A0, A1, 2 * k + 2, 16);      // k=3 loads chunk 8 (window 1 head)
    PROC2(B0, B1, 32 * k + 16, 16);
  }
  TAILPASS(0, 128);                     // partial rows 0..127

  // ---- window 1: chunks 8..15 (steps 128..254 -> slots 0..126) ----
  #pragma unroll 1
  for (int k = 0; k < 3; ++k) {
    LOADC2(B0, B1, 2 * k + 9, 16);
    PROC2(A0, A1, 32 * k, 16);
    LOADC2(A0, A1, 2 * k + 10, 16);
    PROC2(B0, B1, 32 * k + 16, 16);
  }
  LOADC2(B0, B1, 15, 15);               // last chunk: 15 steps
  PROC2(A0, A1, 96, 16);                // chunk 14 -> slots 96..111
  PROC2(B0, B1, 112, 15);               // chunk 15 -> slots 112..126
  TAILPASS(1, 127);                     // partial rows 128..254
}

// one thread per (b, t): sum 8 vb-partials, emit 6 probabilities (R9 form).
__global__ __launch_bounds__(64) void sde_finalize(const float* __restrict__ partial,
                                                   float* __restrict__ out) {
  const int idx = blockIdx.x * 64 + threadIdx.x;   // b*256 + t, 8192 total
  const int b = idx >> 8;
  const int t = idx & 255;
  float* o = out + (size_t)idx * 6;

  if (t == 0) {
    o[0] = 0.5f; o[1] = 0.5f; o[2] = 0.5f; o[3] = 0.5f;
    o[4] = 1.0f; o[5] = 0.0f;
    return;
  }

  float sx = 0.0f, sy = 0.0f, sz = 0.0f;
  #pragma unroll
  for (int j = 0; j < 8; ++j) {
    const float* p = partial + ((size_t)(b * 8 + j) * NSTEPS + (t - 1)) * 3;
    sx += p[0]; sy += p[1]; sz += p[2];
  }
  const float inv = 1.0f / 512.0f;
  const float mx = sx * inv, my = sy * inv, mz = sz * inv;
  o[0] = 0.5f * (1.0f + mx);
  o[1] = 0.5f * (1.0f - mx);
  o[2] = 0.5f * (1.0f + my);
  o[3] = 0.5f * (1.0f - my);
  o[4] = 0.5f * (1.0f + mz);
  o[5] = 0.5f * (1.0f - mz);
}

extern "C" void kernel_launch(void* const* d_in, const int* in_sizes, int n_in,
                              void* d_out, int out_size, void* d_ws, size_t ws_size,
                              hipStream_t stream) {
  (void)in_sizes; (void)n_in; (void)out_size; (void)ws_size;
  const float* inp  = (const float*)d_in[0];   // [32]
  const float* wvec = (const float*)d_in[1];   // [16384][255][2]
  float* out     = (float*)d_out;              // [32][256][6]
  float* partial = (float*)d_ws;               // [256 vb][255][3] f32

  sde_integrate<<<NBLK, 64, 0, stream>>>(inp, wvec, partial);
  sde_finalize<<<128, 64, 0, stream>>>(partial, out);
}

// Round 14
// 23.248 us; speedup vs baseline: 1.5286x; 1.5286x over previous
//
#include <hip/hip_runtime.h>

// Problem constants
#define NSTEPS 255
#define NTRAJ  16384
#define NBLK   256          // integration blocks; 64 trajectories each
#define CH     15           // steps per prefetch chunk; 17*15 = 255

#define GAMMA_F 0.36f
#define OMEGA_F 5.0265f
#define DT_F    0.00390625f          // 2^-8
#define CW      0.0375f              // sqrt(GAMMA)*sqrt(DT) = 0.6/16 (exact)
#define GD      (GAMMA_F * DT_F)
#define OD      (OMEGA_F * DT_F)

// LDS state history (R7/R9-validated): [slot][lane] fp16x4, pitch 520 B.
// Writes: 64 consecutive 8B (free). Tail reads: lane-stride 520 B ->
// start bank 2l mod 32 -> 2-way aliasing = free (m136).
#define PITCH  520
#define STATEB 132608        // 255*520 = 132600, padded

typedef __fp16 half2v __attribute__((ext_vector_type(2)));
typedef float  f32x2  __attribute__((ext_vector_type(2)));

__device__ __forceinline__ unsigned pk2(float a, float b) {
  half2v h = __builtin_amdgcn_cvt_pkrtz(a, b);
  return __builtin_bit_cast(unsigned, h);
}

// One Euler-Maruyama step (R4/R7/R9-validated math, bit-identical).
// w2_ holds the PRESCALED noise (w0, cy) = (wx, wy) * CW.
#define STEP2(w2_, ii_) {                                                       \
  const float w0 = (w2_)[0];                                                    \
  const float cy = (w2_)[1];                                                    \
  const f32x2 sw = __builtin_shufflevector(v, v, 1, 0);    /* (y,x) */          \
  f32x2 t = __builtin_elementwise_fma(epack, sw, v);                            \
  t = __builtin_elementwise_fma(mGD2, v, t);                                    \
  const f32x2 w0s = {w0, w0};                                                   \
  t = __builtin_elementwise_fma(-(v * z), w0s, t);                              \
  const f32x2 cys = {-cy, cy};                                                  \
  t = __builtin_elementwise_fma(sw, cys, t);                                    \
  t[1] = __builtin_fmaf(-OD, z, t[1]);                                          \
  const float a_ = __builtin_fmaf(OD, v[1], z);                                 \
  const float r_ = __builtin_fmaf(-(z * z), w0, w0);                            \
  v = t; z = a_ + r_;                                                           \
  *(uint2*)(sb + (ii_) * PITCH) = make_uint2(pk2(v[0], v[1]), pk2(z, 0.0f));    \
}

#define LOADC(BUF, CHUNK_) {                                                    \
  _Pragma("unroll")                                                             \
  for (int i_ = 0; i_ < CH; ++i_) BUF[i_] = wrow[(CHUNK_) * CH + i_];           \
}

// Chunk prescale (burst of v_pk_mul_f32, independent ops) then 15 steps.
// w0 = wx*CW / cy = wy*CW computed by the SAME IEEE mul as before, just
// hoisted -> bit-identical results, -1 issue/step, -1 dep level at entry.
#define PROC(BUF) {                                                             \
  _Pragma("unroll")                                                             \
  for (int i_ = 0; i_ < CH; ++i_) (BUF)[i_] *= CWv;                             \
  _Pragma("unroll")                                                             \
  for (int i_ = 0; i_ < CH; ++i_) STEP2((BUF)[i_], i_)                          \
  sb += CH * PITCH;                                                             \
}

// grid = 256 blocks x 64 threads (1 wave); block g owns trajectories g*64..+63.
// R9-validated: direct w loads (distance-2 reg prefetch), per-step LDS state
// write, in-wave tail reduction -> partial[g][slot][3] (f32).
__global__ __launch_bounds__(64) void sde_integrate(const float* __restrict__ inp,
                                                    const float* __restrict__ wvec,
                                                    float* __restrict__ partial) {
  __shared__ alignas(16) char smem[STATEB];
  const int g = blockIdx.x, l = threadIdx.x;
  // trajectory n = g*64+l; eps = inputs[n % 32] = inputs[l & 31]
  const float eps = inp[l & 31];
  const f32x2 epack = {-eps * DT_F, eps * DT_F};
  const f32x2 mGD2  = {-GD, -GD};
  const f32x2 CWv   = {CW, CW};

  const f32x2* __restrict__ wrow =
      reinterpret_cast<const f32x2*>(wvec) + (size_t)(g * 64 + l) * NSTEPS;
  char* sb = smem + l * 8;             // slot 0, this lane's column

  f32x2 v = {0.0f, 0.0f};
  float z = 1.0f;

  f32x2 bufA[CH], bufB[CH], bufC[CH];  // static indexing only (regs)

  // prefetch distance 2: chunks c and c+1 in flight before computing c
  LOADC(bufA, 0);
  LOADC(bufB, 1);
  #pragma unroll 1
  for (int k = 0; k < 5; ++k) {        // chunks 3k..3k+2, loads 3k+2..3k+4
    LOADC(bufC, 3 * k + 2); PROC(bufA);
    LOADC(bufA, 3 * k + 3); PROC(bufB);
    LOADC(bufB, 3 * k + 4); PROC(bufC);
  }
  PROC(bufA);                          // chunk 15
  PROC(bufB);                          // chunk 16 (slots 240..254)

  __syncthreads();                     // single wave: cheap; orders LDS for tail

  // Tail (R9-validated): lane l reduces slots l, l+64, l+128, l+192 (<255).
  #pragma unroll
  for (int k = 0; k < 4; ++k) {
    const int s = l + 64 * k;
    if (s < NSTEPS) {
      const char* rb = smem + (size_t)s * PITCH;
      f32x2 sxy = {0.0f, 0.0f};
      float fz = 0.0f;
      #pragma unroll
      for (int j = 0; j < 64; ++j) {
        const uint2 u = *(const uint2*)(rb + j * 8);
        const half2v xy = __builtin_bit_cast(half2v, u.x);
        const half2v zp = __builtin_bit_cast(half2v, u.y);
        const f32x2 vxy = {(float)xy[0], (float)xy[1]};
        sxy += vxy;
        fz += (float)zp[0];
      }
      float* p = partial + ((size_t)g * NSTEPS + s) * 3;
      p[0] = sxy[0]; p[1] = sxy[1]; p[2] = fz;
    }
  }
}

// one thread per (b, t): sum 8 block-partials, emit 6 probabilities.
__global__ __launch_bounds__(64) void sde_finalize(const float* __restrict__ partial,
                                                   float* __restrict__ out) {
  const int idx = blockIdx.x * 64 + threadIdx.x;   // b*256 + t, 8192 total
  const int b = idx >> 8;
  const int t = idx & 255;
  float* o = out + (size_t)idx * 6;

  if (t == 0) {
    o[0] = 0.5f; o[1] = 0.5f; o[2] = 0.5f; o[3] = 0.5f;
    o[4] = 1.0f; o[5] = 0.0f;
    return;
  }

  float sx = 0.0f, sy = 0.0f, sz = 0.0f;
  #pragma unroll
  for (int j = 0; j < 8; ++j) {
    const float* p = partial + ((size_t)(b * 8 + j) * NSTEPS + (t - 1)) * 3;
    sx += p[0]; sy += p[1]; sz += p[2];
  }
  const float inv = 1.0f / 512.0f;
  const float mx = sx * inv, my = sy * inv, mz = sz * inv;
  o[0] = 0.5f * (1.0f + mx);
  o[1] = 0.5f * (1.0f - mx);
  o[2] = 0.5f * (1.0f + my);
  o[3] = 0.5f * (1.0f - my);
  o[4] = 0.5f * (1.0f + mz);
  o[5] = 0.5f * (1.0f - mz);
}

extern "C" void kernel_launch(void* const* d_in, const int* in_sizes, int n_in,
                              void* d_out, int out_size, void* d_ws, size_t ws_size,
                              hipStream_t stream) {
  (void)in_sizes; (void)n_in; (void)out_size; (void)ws_size;
  const float* inp  = (const float*)d_in[0];   // [32]
  const float* wvec = (const float*)d_in[1];   // [16384][255][2]
  float* out     = (float*)d_out;              // [32][256][6]
  float* partial = (float*)d_ws;               // [256][255][3] f32

  sde_integrate<<<NBLK, 64, 0, stream>>>(inp, wvec, partial);
  sde_finalize<<<128, 64, 0, stream>>>(partial, out);
}